// Round 11
// baseline (75.062 us; speedup 1.0000x reference)
//
#include <hip/hip_runtime.h>
#include <hip/hip_bf16.h>

// LiquidS4: y = (scan(a, u@B.T)) @ C.T + D*u — SINGLE fused kernel.
// u (4,4096,1024) f32; Lambda (64); log_dt (1); B (64,1024); C (1024,64); D (1024)
// 512 blocks (one per 32-step chunk), all co-resident (2/CU): decoupled-lookback
// carry via device-scope atomics. Phases: Bu-GEMM -> local scan -> publish/lookback
// -> exact xs (bf16, LDS) -> y = xs @ C.T (+D*u) for the block's own 32 rows.

constexpr int BATCH  = 4;
constexpr int L      = 4096;
constexpr int DM     = 1024;
constexpr int N      = 64;
constexpr int ROWS   = BATCH * L;    // 16384
constexpr int CHUNK  = 32;
constexpr int NCHUNK = L / CHUNK;    // 128
constexpr int NBLK   = ROWS / CHUNK; // 512

typedef __attribute__((ext_vector_type(8))) short     bf16x8;
typedef __attribute__((ext_vector_type(4))) float     f32x4;

__device__ __forceinline__ unsigned int pk2(float x, float y) {
  __hip_bfloat162 h = __float22bfloat162_rn(make_float2(x, y));   // v_cvt_pk_bf16_f32
  return *reinterpret_cast<unsigned int*>(&h);
}

__global__ __launch_bounds__(256, 2) void fused_s4(const float* __restrict__ u,
                                                   const float* __restrict__ Bm,
                                                   const float* __restrict__ Lambda,
                                                   const float* __restrict__ log_dt,
                                                   const float* __restrict__ Cm,
                                                   const float* __restrict__ Dv,
                                                   float* __restrict__ Fbuf,
                                                   int* __restrict__ flags,
                                                   float* __restrict__ y) {
  __shared__ __align__(16) char smem[27648];
  // phase-1 staging (R10 layout)
  unsigned short (*As0)[72] = reinterpret_cast<unsigned short (*)[72]>(smem);
  unsigned short (*As1)[72] = reinterpret_cast<unsigned short (*)[72]>(smem + 4608);
  unsigned short (*Bs0)[72] = reinterpret_cast<unsigned short (*)[72]>(smem + 9216);
  unsigned short (*Bs1)[72] = reinterpret_cast<unsigned short (*)[72]>(smem + 18432);
  // post-GEMM unions (staging dead by then)
  float (*T)[68] = reinterpret_cast<float (*)[68]>(smem);            // 8704 B
  float* W  = reinterpret_cast<float*>(smem + 8704);                 // 1024 B
  float* W2 = reinterpret_cast<float*>(smem + 9728);                 // 256 B (carry)
  unsigned short (*Xs)[72] = reinterpret_cast<unsigned short (*)[72]>(smem + 10240); // 4608 B

  const int tid  = threadIdx.x;
  const int lane = tid & 63;
  const int wv   = tid >> 6;
  const int l15  = lane & 15;
  const int g    = lane >> 4;
  const int rh   = wv >> 1;            // row-half 0..1
  const int cp   = wv & 1;             // col-pair 0..1
  const int blk  = blockIdx.x;
  const int row0 = blk * CHUNK;

  const int sra = tid >> 4;            // staging row 0..15
  const int sq  = tid & 15;            // k-quad

  // ================= Phase 1: Bu = u @ B.T (bf16 MFMA) =================
  f32x4 acc1[2] = {};
  float4 pa[2][2], pb[2][4];

  constexpr int NCH = DM / 64;         // 16 K-chunks of 64
  #pragma unroll
  for (int s = 0; s < 2; ++s) {
    const int kb = s * 64;
    #pragma unroll
    for (int i = 0; i < 2; ++i)
      pa[s][i] = *reinterpret_cast<const float4*>(
          &u[(long)(row0 + sra + i * 16) * DM + kb + sq * 4]);
    #pragma unroll
    for (int i = 0; i < 4; ++i)
      pb[s][i] = *reinterpret_cast<const float4*>(
          &Bm[(long)(sra + i * 16) * DM + kb + sq * 4]);
  }

  #pragma unroll                       // full unroll: buffer select is compile-time
  for (int c = 0; c < NCH; ++c) {
    const int s = c & 1;
    unsigned short (*As)[72] = s ? As1 : As0;
    unsigned short (*Bs)[72] = s ? Bs1 : Bs0;
    if (c) __syncthreads();
    #pragma unroll
    for (int i = 0; i < 2; ++i) {
      uint2 ha = {pk2(pa[s][i].x, pa[s][i].y), pk2(pa[s][i].z, pa[s][i].w)};
      *reinterpret_cast<uint2*>(&As[sra + i * 16][sq * 4]) = ha;
    }
    #pragma unroll
    for (int i = 0; i < 4; ++i) {
      uint2 hb = {pk2(pb[s][i].x, pb[s][i].y), pk2(pb[s][i].z, pb[s][i].w)};
      *reinterpret_cast<uint2*>(&Bs[sra + i * 16][sq * 4]) = hb;
    }
    __syncthreads();
    if (c + 2 < NCH) {
      const int kb = (c + 2) * 64;
      #pragma unroll
      for (int i = 0; i < 2; ++i)
        pa[s][i] = *reinterpret_cast<const float4*>(
            &u[(long)(row0 + sra + i * 16) * DM + kb + sq * 4]);
      #pragma unroll
      for (int i = 0; i < 4; ++i)
        pb[s][i] = *reinterpret_cast<const float4*>(
            &Bm[(long)(sra + i * 16) * DM + kb + sq * 4]);
    }
    #pragma unroll
    for (int ks = 0; ks < 2; ++ks) {
      const bf16x8 af = *reinterpret_cast<const bf16x8*>(
          &As[rh * 16 + l15][ks * 32 + g * 8]);
      #pragma unroll
      for (int t = 0; t < 2; ++t) {
        const bf16x8 bfr = *reinterpret_cast<const bf16x8*>(
            &Bs[(cp * 2 + t) * 16 + l15][ks * 32 + g * 8]);
        acc1[t] = __builtin_amdgcn_mfma_f32_16x16x32_bf16(af, bfr, acc1[t], 0, 0, 0);
      }
    }
  }

  // Bu tile -> LDS transpose (D-frag: col = (cp*2+t)*16+l15, row = rh*16+g*4+r)
  __syncthreads();
  #pragma unroll
  for (int t = 0; t < 2; ++t)
    #pragma unroll
    for (int r = 0; r < 4; ++r)
      T[rh * 16 + g * 4 + r][(cp * 2 + t) * 16 + l15] = acc1[t][r];
  __syncthreads();

  // ================= Phase 2: local scan (wave w owns steps w*8..w*8+7) ========
  const float dtv = __expf(log_dt[0]);
  const float wn  = -dtv * __expf(Lambda[lane]);
  const float a   = __expf(wn);
  const float a8  = __expf(wn * 8.0f);
  const float aS  = __expf(wn * 32.0f);

  float p[8];
  {
    float x = 0.0f;
    #pragma unroll
    for (int j = 0; j < 8; ++j) { x = fmaf(a, x, T[wv * 8 + j][lane]); p[j] = x; }
    W[wv * 64 + lane] = x;
  }
  __syncthreads();
  {
    float P = 0.0f;
    #pragma unroll
    for (int w2 = 0; w2 < 3; ++w2)
      if (w2 < wv) P = fmaf(a8, P, W[w2 * 64 + lane]);
    float cf = P;
    #pragma unroll
    for (int j = 0; j < 8; ++j) { cf *= a; p[j] += cf; }   // chunk-local exact (x0=0)
  }

  // ================= Phase 3: publish chunk-final + lookback carry =============
  if (wv == 3) {
    __hip_atomic_store(&Fbuf[blk * 64 + lane], p[7],
                       __ATOMIC_RELAXED, __HIP_MEMORY_SCOPE_AGENT);
    __threadfence();                   // drain this wave's stores device-wide
    if (lane == 0)
      __hip_atomic_store(&flags[blk], 1, __ATOMIC_RELEASE, __HIP_MEMORY_SCOPE_AGENT);
  }
  if (wv == 0) {
    float carry = 0.0f;
    const int c = blk & (NCHUNK - 1);
    if (c) {
      const int base = blk - c;
      for (;;) {                       // spin until all predecessor flags set
        int f1 = (lane < c) ? __hip_atomic_load(&flags[base + lane],
                     __ATOMIC_ACQUIRE, __HIP_MEMORY_SCOPE_AGENT) : 1;
        int f2 = (lane + 64 < c) ? __hip_atomic_load(&flags[base + 64 + lane],
                     __ATOMIC_ACQUIRE, __HIP_MEMORY_SCOPE_AGENT) : 1;
        if (__all(f1 != 0 && f2 != 0)) break;
        __builtin_amdgcn_s_sleep(16);
      }
      // batched loads (16-wide) so the FMA chain isn't load-latency-serialized
      int j = 0;
      for (; j + 16 <= c; j += 16) {
        float fj[16];
        #pragma unroll
        for (int k = 0; k < 16; ++k)
          fj[k] = __hip_atomic_load(&Fbuf[(base + j + k) * 64 + lane],
                                    __ATOMIC_RELAXED, __HIP_MEMORY_SCOPE_AGENT);
        #pragma unroll
        for (int k = 0; k < 16; ++k) carry = fmaf(aS, carry, fj[k]);
      }
      for (; j < c; ++j) {
        const float fj = __hip_atomic_load(&Fbuf[(base + j) * 64 + lane],
                                           __ATOMIC_RELAXED, __HIP_MEMORY_SCOPE_AGENT);
        carry = fmaf(aS, carry, fj);
      }
    }
    W2[lane] = carry;
  }
  __syncthreads();

  // ================= Phase 4: apply carry, xs -> bf16 in LDS ===================
  {
    float tmp = W2[lane];
    #pragma unroll
    for (int i = 0; i < 3; ++i) if (i < wv) tmp *= a8;   // a^(8*wv)
    #pragma unroll
    for (int j = 0; j < 8; ++j) { tmp *= a; T[wv * 8 + j][lane] = p[j] + tmp; }
  }
  __syncthreads();
  {
    const int r = tid >> 3, q = tid & 7;                 // 32 rows x 8 octets
    const float4 v0 = *reinterpret_cast<const float4*>(&T[r][q * 8]);
    const float4 v1 = *reinterpret_cast<const float4*>(&T[r][q * 8 + 4]);
    uint4 o = {pk2(v0.x, v0.y), pk2(v0.z, v0.w), pk2(v1.x, v1.y), pk2(v1.z, v1.w)};
    *reinterpret_cast<uint4*>(&Xs[r][q * 8]) = o;
  }
  __syncthreads();

  // ================= Phase 5: y[row0..row0+32) = xs @ C.T (+D*u) ===============
  // wave w owns d-slice [w*256, (w+1)*256): 16 col-tiles x 2 row-tiles, streaming.
  const int d0w = wv * 256;
  bf16x8 af2[2][2];
  #pragma unroll
  for (int m = 0; m < 2; ++m)
    #pragma unroll
    for (int ks = 0; ks < 2; ++ks)
      af2[m][ks] = *reinterpret_cast<const bf16x8*>(&Xs[m * 16 + l15][ks * 32 + g * 8]);

  #pragma unroll
  for (int t = 0; t < 16; ++t) {
    const long crow = (long)(d0w + t * 16 + l15) * N;
    const float4 c00 = *reinterpret_cast<const float4*>(&Cm[crow + g * 8]);
    const float4 c01 = *reinterpret_cast<const float4*>(&Cm[crow + g * 8 + 4]);
    const float4 c10 = *reinterpret_cast<const float4*>(&Cm[crow + 32 + g * 8]);
    const float4 c11 = *reinterpret_cast<const float4*>(&Cm[crow + 32 + g * 8 + 4]);
    uint4 w0 = {pk2(c00.x, c00.y), pk2(c00.z, c00.w), pk2(c01.x, c01.y), pk2(c01.z, c01.w)};
    uint4 w1 = {pk2(c10.x, c10.y), pk2(c10.z, c10.w), pk2(c11.x, c11.y), pk2(c11.z, c11.w)};
    const bf16x8 bf0 = *reinterpret_cast<const bf16x8*>(&w0);
    const bf16x8 bf1 = *reinterpret_cast<const bf16x8*>(&w1);
    f32x4 a0 = {}, a1 = {};
    a0 = __builtin_amdgcn_mfma_f32_16x16x32_bf16(af2[0][0], bf0, a0, 0, 0, 0);
    a0 = __builtin_amdgcn_mfma_f32_16x16x32_bf16(af2[0][1], bf1, a0, 0, 0, 0);
    a1 = __builtin_amdgcn_mfma_f32_16x16x32_bf16(af2[1][0], bf0, a1, 0, 0, 0);
    a1 = __builtin_amdgcn_mfma_f32_16x16x32_bf16(af2[1][1], bf1, a1, 0, 0, 0);

    const int col = d0w + t * 16 + l15;
    const float dD = Dv[col];
    #pragma unroll
    for (int r = 0; r < 4; ++r) {
      const long row = row0 + g * 4 + r;
      float v = a0[r];
      if (dD != 0.0f) v = fmaf(dD, u[row * DM + col], v);
      y[row * DM + col] = v;
    }
    #pragma unroll
    for (int r = 0; r < 4; ++r) {
      const long row = row0 + 16 + g * 4 + r;
      float v = a1[r];
      if (dD != 0.0f) v = fmaf(dD, u[row * DM + col], v);
      y[row * DM + col] = v;
    }
  }
}

extern "C" void kernel_launch(void* const* d_in, const int* in_sizes, int n_in,
                              void* d_out, int out_size, void* d_ws, size_t ws_size,
                              hipStream_t stream) {
  const float* u      = (const float*)d_in[0];
  const float* Lambda = (const float*)d_in[1];
  const float* log_dt = (const float*)d_in[2];
  const float* Bm     = (const float*)d_in[3];
  const float* Cm     = (const float*)d_in[4];
  const float* Dv     = (const float*)d_in[5];
  float* y = (float*)d_out;

  float* Fbuf = (float*)d_ws;                        // 512*64 f32 = 128 KB
  int*   flags = (int*)(Fbuf + (size_t)NBLK * N);    // 512 ints = 2 KB

  hipMemsetAsync(flags, 0, NBLK * sizeof(int), stream);
  fused_s4<<<NBLK, 256, 0, stream>>>(u, Bm, Lambda, log_dt, Cm, Dv, Fbuf, flags, y);
}

// Round 12
// 36.239 us; speedup vs baseline: 2.0713x; 2.0713x over previous
//
#include <hip/hip_runtime.h>
#include <hip/hip_bf16.h>

// LiquidS4: y = (scan(a, u@B.T)) @ C.T + D*u
// u (4,4096,1024) f32; Lambda (64); log_dt (1); B (64,1024); C (1024,64); D (1024)
// R12: 2-kernel pipeline. K1 = R9 bu_scan verbatim (GEMM + 4-wave chunk scan ->
// xsb bf16 + chunk-finals F). K2 = y_gemm with per-block carry recompute from F
// (no carry_scan kernel, no atomics — F is complete when K2 starts).

constexpr int BATCH  = 4;
constexpr int L      = 4096;
constexpr int DM     = 1024;
constexpr int N      = 64;
constexpr int ROWS   = BATCH * L;    // 16384
constexpr int CHUNK  = 64;           // one chunk per bu_scan block / y_gemm row-tile
constexpr int NCHUNK = L / CHUNK;    // 64

typedef __attribute__((ext_vector_type(8))) short     bf16x8;
typedef __attribute__((ext_vector_type(4))) float     f32x4;

__device__ __forceinline__ unsigned int pk2(float x, float y) {
  __hip_bfloat162 h = __float22bfloat162_rn(make_float2(x, y));   // v_cvt_pk_bf16_f32
  return *reinterpret_cast<unsigned int*>(&h);
}

// ---------------- Kernel 1: Bu = u @ B.T (bf16 MFMA) + 4-wave chunk scan ------
__global__ __launch_bounds__(256) void bu_scan(const float* __restrict__ u,
                                               const float* __restrict__ Bm,
                                               const float* __restrict__ Lambda,
                                               const float* __restrict__ log_dt,
                                               unsigned short* __restrict__ xsb,
                                               float* __restrict__ F) {
  __shared__ __align__(16) char smem[36864];
  typedef unsigned short HalfT[64][72];
  HalfT* As = reinterpret_cast<HalfT*>(smem);               // [2][64][72] = 18432 B
  HalfT* Bs = reinterpret_cast<HalfT*>(smem + 18432);       // [2][64][72] = 18432 B
  float (*T)[68] = reinterpret_cast<float (*)[68]>(smem);   // 17408 B (unions As)
  float* W = reinterpret_cast<float*>(smem + 17408);        // 1024 B  (unions As tail)

  const int tid  = threadIdx.x;
  const int lane = tid & 63;
  const int wv   = tid >> 6;           // wave 0..3
  const int l15  = lane & 15;
  const int g    = lane >> 4;
  const int row0 = blockIdx.x * 64;

  const int sr = tid >> 4;             // staging row 0..15 (+i*16)
  const int sq = tid & 15;             // staging k-quad

  f32x4 acc[4] = {};
  float4 pa[2][4], pb[2][4];

  constexpr int NCH = DM / 64;         // 16 K-chunks
  #pragma unroll
  for (int s = 0; s < 2; ++s) {
    const int kb = s * 64;
    #pragma unroll
    for (int i = 0; i < 4; ++i) {
      const int r = sr + i * 16;
      pa[s][i] = *reinterpret_cast<const float4*>(&u[(long)(row0 + r) * DM + kb + sq * 4]);
      pb[s][i] = *reinterpret_cast<const float4*>(&Bm[(long)r * DM + kb + sq * 4]);
    }
  }

  #pragma unroll                       // FULL unroll: s becomes compile-time (rule #20)
  for (int c = 0; c < NCH; ++c) {
    const int s = c & 1;
    if (c) __syncthreads();
    #pragma unroll
    for (int i = 0; i < 4; ++i) {
      const int r = sr + i * 16;
      uint2 ha = {pk2(pa[s][i].x, pa[s][i].y), pk2(pa[s][i].z, pa[s][i].w)};
      uint2 hb = {pk2(pb[s][i].x, pb[s][i].y), pk2(pb[s][i].z, pb[s][i].w)};
      *reinterpret_cast<uint2*>(&As[s][r][sq * 4]) = ha;
      *reinterpret_cast<uint2*>(&Bs[s][r][sq * 4]) = hb;
    }
    __syncthreads();
    if (c + 2 < NCH) {                 // refill the set just consumed (2 ahead)
      const int kb = (c + 2) * 64;
      #pragma unroll
      for (int i = 0; i < 4; ++i) {
        const int r = sr + i * 16;
        pa[s][i] = *reinterpret_cast<const float4*>(&u[(long)(row0 + r) * DM + kb + sq * 4]);
        pb[s][i] = *reinterpret_cast<const float4*>(&Bm[(long)r * DM + kb + sq * 4]);
      }
    }
    #pragma unroll
    for (int ks = 0; ks < 2; ++ks) {
      const bf16x8 af = *reinterpret_cast<const bf16x8*>(
          &As[s][wv * 16 + l15][ks * 32 + g * 8]);
      #pragma unroll
      for (int t = 0; t < 4; ++t) {
        const bf16x8 bfr = *reinterpret_cast<const bf16x8*>(
            &Bs[s][t * 16 + l15][ks * 32 + g * 8]);
        acc[t] = __builtin_amdgcn_mfma_f32_16x16x32_bf16(af, bfr, acc[t], 0, 0, 0);
      }
    }
  }

  // Bu tile -> LDS transpose (col n = t*16+l15, row = wv*16+g*4+r)
  __syncthreads();
  #pragma unroll
  for (int t = 0; t < 4; ++t)
    #pragma unroll
    for (int r = 0; r < 4; ++r)
      T[wv * 16 + g * 4 + r][t * 16 + l15] = acc[t][r];
  __syncthreads();

  // ---- 4-wave parallel scan: wave w owns timesteps w*16..w*16+15, lane = n ---
  const float dtv = __expf(log_dt[0]);
  const float wn  = -dtv * __expf(Lambda[lane]);
  const float a   = __expf(wn);
  const float a16 = __expf(wn * 16.0f);

  float p[16];
  {
    float x = 0.0f;
    #pragma unroll
    for (int j = 0; j < 16; ++j) { x = fmaf(a, x, T[wv * 16 + j][lane]); p[j] = x; }
    W[wv * 64 + lane] = x;             // wave-local final
  }
  __syncthreads();
  float P = 0.0f;                      // prefix entering this wave's 16 steps
  #pragma unroll
  for (int w2 = 0; w2 < 3; ++w2)
    if (w2 < wv) P = fmaf(a16, P, W[w2 * 64 + lane]);
  __syncthreads();
  float cfac = P;
  #pragma unroll
  for (int j = 0; j < 16; ++j) { cfac *= a; T[wv * 16 + j][lane] = p[j] + cfac; }
  if (wv == 3) F[blockIdx.x * N + lane] = p[15] + cfac;   // chunk final (local)
  __syncthreads();

  // coalesced bf16 stores of the scanned tile: 64 rows x 64 n
  #pragma unroll
  for (int i = 0; i < 4; ++i) {
    const int idx = tid + i * 256;
    const int r = idx >> 4, q = idx & 15;
    const float4 v = *reinterpret_cast<const float4*>(&T[r][q * 4]);
    uint2 o = {pk2(v.x, v.y), pk2(v.z, v.w)};
    *reinterpret_cast<uint2*>(&xsb[(long)(row0 + r) * N + q * 4]) = o;
  }
}

// ---------------- Kernel 2: y = (xs + a^(r+1)*carry) @ C.T (+D*u if D!=0) -----
// Tile 64 rows (= one chunk) x 128 d. Wave 0 recomputes this chunk's carry from
// the L2-hot F table (<=63-deep fmaf chain, 16-batched loads) — no carry kernel.
__global__ __launch_bounds__(256) void y_gemm(const unsigned short* __restrict__ xsb,
                                              const float* __restrict__ F,
                                              const float* __restrict__ Lambda,
                                              const float* __restrict__ log_dt,
                                              const float* __restrict__ Cm,
                                              const float* __restrict__ Dv,
                                              const float* __restrict__ u,
                                              float* __restrict__ y) {
  __shared__ __align__(16) char smem[33792];
  unsigned short (*Xs)[72] = reinterpret_cast<unsigned short (*)[72]>(smem);         // 9216 B
  unsigned short (*Cs)[72] = reinterpret_cast<unsigned short (*)[72]>(smem + 9216);  // 18432 B
  float (*T)[132] = reinterpret_cast<float (*)[132]>(smem);                          // 33792 B union
  __shared__ float ciS[64], wS[64], Dsh[128];

  const int tid  = threadIdx.x;
  const int lane = tid & 63;
  const int wv   = tid >> 6;
  const int l15  = lane & 15;
  const int g    = lane >> 4;
  const int row0 = (blockIdx.x & 255) * 64;
  const int d0   = (blockIdx.x >> 8) * 128;
  const int b    = row0 >> 12;          // batch
  const int c    = (row0 >> 6) & 63;    // chunk within batch

  if (tid < 64) {                       // wave 0: decay + carry chain
    const int n = tid;
    const float dtv = __expf(log_dt[0]);
    const float wn  = -dtv * __expf(Lambda[n]);
    wS[n] = wn;
    const float aS = __expf(wn * 64.0f);
    float P = 0.0f;
    int j = 0;
    for (; j + 16 <= c; j += 16) {      // 16-batched loads, then chain
      float fj[16];
      #pragma unroll
      for (int k = 0; k < 16; ++k) fj[k] = F[((b << 6) + j + k) * N + n];
      #pragma unroll
      for (int k = 0; k < 16; ++k) P = fmaf(aS, P, fj[k]);
    }
    for (; j < c; ++j) P = fmaf(aS, P, F[((b << 6) + j) * N + n]);
    ciS[n] = P;
  } else if (tid < 192) {
    Dsh[tid - 64] = Dv[d0 + (tid - 64)];
  }
  __syncthreads();

  // stage Xs with carry fixup: 512 ushort8 groups (2 per thread)
  #pragma unroll
  for (int i = 0; i < 2; ++i) {
    const int idx = tid + i * 256;
    const int r = idx >> 3, q = idx & 7;       // r 0..63, q = n-octet
    const uint4 xv = *reinterpret_cast<const uint4*>(&xsb[(long)(row0 + r) * N + q * 8]);
    const float rp1 = (float)(r + 1);
    float f[8];
    #pragma unroll
    for (int j = 0; j < 4; ++j) {
      const unsigned int wbits = (&xv.x)[j];
      f[2 * j]     = __uint_as_float(wbits << 16);
      f[2 * j + 1] = __uint_as_float(wbits & 0xFFFF0000u);
    }
    #pragma unroll
    for (int j = 0; j < 8; ++j) {
      const int n = q * 8 + j;
      f[j] = fmaf(__expf(wS[n] * rp1), ciS[n], f[j]);
    }
    uint4 o = {pk2(f[0], f[1]), pk2(f[2], f[3]), pk2(f[4], f[5]), pk2(f[6], f[7])};
    *reinterpret_cast<uint4*>(&Xs[r][q * 8]) = o;
  }
  // stage Cs from f32 (L2-hot): 128 d x 64 n
  #pragma unroll
  for (int i = 0; i < 8; ++i) {
    const int idx = tid + i * 256;
    const int r = idx >> 4, q = idx & 15;
    const float4 v = *reinterpret_cast<const float4*>(&Cm[(long)(d0 + r) * N + q * 4]);
    uint2 o = {pk2(v.x, v.y), pk2(v.z, v.w)};
    *reinterpret_cast<uint2*>(&Cs[r][q * 4]) = o;
  }
  __syncthreads();

  bf16x8 af[2];
  #pragma unroll
  for (int ks = 0; ks < 2; ++ks)
    af[ks] = *reinterpret_cast<const bf16x8*>(&Xs[wv * 16 + l15][ks * 32 + g * 8]);

  f32x4 acc[8] = {};
  #pragma unroll
  for (int t = 0; t < 8; ++t) {
    #pragma unroll
    for (int ks = 0; ks < 2; ++ks) {
      const bf16x8 bfr = *reinterpret_cast<const bf16x8*>(
          &Cs[t * 16 + l15][ks * 32 + g * 8]);
      acc[t] = __builtin_amdgcn_mfma_f32_16x16x32_bf16(af[ks], bfr, acc[t], 0, 0, 0);
    }
  }

  // transpose via LDS -> coalesced float4 stores
  __syncthreads();
  #pragma unroll
  for (int t = 0; t < 8; ++t)
    #pragma unroll
    for (int r = 0; r < 4; ++r)
      T[wv * 16 + g * 4 + r][t * 16 + l15] = acc[t][r];
  __syncthreads();

  #pragma unroll
  for (int i = 0; i < 8; ++i) {
    const int id = tid + i * 256;
    const int r = id >> 5;
    const int q = id & 31;
    float4 v = *reinterpret_cast<const float4*>(&T[r][q * 4]);
    const float4 dd = *reinterpret_cast<const float4*>(&Dsh[q * 4]);
    if (dd.x != 0.0f || dd.y != 0.0f || dd.z != 0.0f || dd.w != 0.0f) {
      const float4 uu = *reinterpret_cast<const float4*>(
          &u[(long)(row0 + r) * DM + d0 + q * 4]);
      v.x = fmaf(dd.x, uu.x, v.x);
      v.y = fmaf(dd.y, uu.y, v.y);
      v.z = fmaf(dd.z, uu.z, v.z);
      v.w = fmaf(dd.w, uu.w, v.w);
    }
    *reinterpret_cast<float4*>(&y[(long)(row0 + r) * DM + d0 + q * 4]) = v;
  }
}

extern "C" void kernel_launch(void* const* d_in, const int* in_sizes, int n_in,
                              void* d_out, int out_size, void* d_ws, size_t ws_size,
                              hipStream_t stream) {
  const float* u      = (const float*)d_in[0];
  const float* Lambda = (const float*)d_in[1];
  const float* log_dt = (const float*)d_in[2];
  const float* Bm     = (const float*)d_in[3];
  const float* Cm     = (const float*)d_in[4];
  const float* Dv     = (const float*)d_in[5];
  float* y = (float*)d_out;

  const size_t planeB = (size_t)ROWS * N;              // 1M elems
  unsigned short* xsb = (unsigned short*)d_ws;         // 2 MB bf16
  float* F = (float*)(xsb + planeB);                   // 256*64 f32 = 64 KB

  bu_scan<<<ROWS / 64, 256, 0, stream>>>(u, Bm, Lambda, log_dt, xsb, F);
  y_gemm<<<(ROWS / 64) * (DM / 128), 256, 0, stream>>>(xsb, F, Lambda, log_dt,
                                                       Cm, Dv, u, y);
}